// Round 1
// baseline (265.569 us; speedup 1.0000x reference)
//
#include <hip/hip_runtime.h>
#include <math.h>

#define N_NODES 50000
#define N_EDGES 800000
#define IN_F 128
#define OUT_F 64
#define LRELU_ALPHA 0.2f

__device__ inline float wred_max(float v) {
#pragma unroll
    for (int o = 32; o > 0; o >>= 1) v = fmaxf(v, __shfl_down(v, o, 64));
    return v;
}
__device__ inline float wred_sum(float v) {
#pragma unroll
    for (int o = 32; o > 0; o >>= 1) v += __shfl_down(v, o, 64);
    return v;
}

// K1: Wh = x @ W (per 4-row block), plus s[n] = Wh[n]·a_top, t[n] = Wh[n]·a_bot
__global__ __launch_bounds__(256) void k_wh(const float* __restrict__ x,
                                            const float* __restrict__ W,
                                            const float* __restrict__ a,
                                            float* __restrict__ Wh,
                                            float* __restrict__ sv,
                                            float* __restrict__ tv) {
    __shared__ float Ws[IN_F * OUT_F];   // 32 KB
    __shared__ float xs[4][IN_F];        // 2 KB
    __shared__ float atop[OUT_F], abot[OUT_F];

    for (int i = threadIdx.x; i < IN_F * OUT_F; i += 256) Ws[i] = W[i];
    if (threadIdx.x < OUT_F) {
        atop[threadIdx.x] = a[threadIdx.x];
        abot[threadIdx.x] = a[OUT_F + threadIdx.x];
    }
    int row0 = blockIdx.x * 4;
    for (int i = threadIdx.x; i < 4 * IN_F; i += 256) {
        int r = row0 + i / IN_F;
        xs[i / IN_F][i % IN_F] = (r < N_NODES) ? x[r * IN_F + (i % IN_F)] : 0.0f;
    }
    __syncthreads();

    int lr = threadIdx.x >> 6;  // local row 0..3 (one wave per row)
    int c  = threadIdx.x & 63;  // output feature
    int r  = row0 + lr;
    float acc = 0.0f;
#pragma unroll 8
    for (int k = 0; k < IN_F; k++)
        acc = fmaf(xs[lr][k], Ws[k * OUT_F + c], acc);

    if (r < N_NODES) Wh[r * OUT_F + c] = acc;
    // wave(=row) reductions for s, t
    float ss = wred_sum(acc * atop[c]);
    float tt = wred_sum(acc * abot[c]);
    if (c == 0 && r < N_NODES) { sv[r] = ss; tv[r] = tt; }
}

// K2: e_j = leaky_relu(s[src_j] + t[dst_j]); per-block max -> pmax
__global__ __launch_bounds__(256) void k_edge(const int* __restrict__ src,
                                              const int* __restrict__ dst,
                                              const float* __restrict__ sv,
                                              const float* __restrict__ tv,
                                              float* __restrict__ e,
                                              float* __restrict__ pmax) {
    int base = blockIdx.x * 1024 + threadIdx.x;
    float lmax = -INFINITY;
#pragma unroll
    for (int i = 0; i < 4; i++) {
        int j = base + i * 256;
        if (j < N_EDGES) {
            float v = sv[src[j]] + tv[dst[j]];
            v = v > 0.0f ? v : LRELU_ALPHA * v;
            e[j] = v;
            lmax = fmaxf(lmax, v);
        }
    }
    __shared__ float red[4];
    float wm = wred_max(lmax);
    if ((threadIdx.x & 63) == 0) red[threadIdx.x >> 6] = wm;
    __syncthreads();
    if (threadIdx.x == 0)
        pmax[blockIdx.x] = fmaxf(fmaxf(red[0], red[1]), fmaxf(red[2], red[3]));
}

// K3a: reduce partial maxes -> gmax[0]
__global__ __launch_bounds__(1024) void k_rmax(const float* __restrict__ pmax, int n,
                                               float* __restrict__ gmax) {
    float lmax = -INFINITY;
    for (int i = threadIdx.x; i < n; i += 1024) lmax = fmaxf(lmax, pmax[i]);
    __shared__ float red[16];
    float wm = wred_max(lmax);
    if ((threadIdx.x & 63) == 0) red[threadIdx.x >> 6] = wm;
    __syncthreads();
    if (threadIdx.x == 0) {
        float m = -INFINITY;
        for (int i = 0; i < 16; i++) m = fmaxf(m, red[i]);
        gmax[0] = m;
    }
}

// K3b: e_j <- exp(e_j - gmax); per-block sum -> psum
__global__ __launch_bounds__(256) void k_exp(float* __restrict__ e,
                                             const float* __restrict__ gmax,
                                             float* __restrict__ psum) {
    float gm = gmax[0];
    int base = blockIdx.x * 1024 + threadIdx.x;
    float lsum = 0.0f;
#pragma unroll
    for (int i = 0; i < 4; i++) {
        int j = base + i * 256;
        if (j < N_EDGES) {
            float p = expf(e[j] - gm);
            e[j] = p;
            lsum += p;
        }
    }
    __shared__ float red[4];
    float wsm = wred_sum(lsum);
    if ((threadIdx.x & 63) == 0) red[threadIdx.x >> 6] = wsm;
    __syncthreads();
    if (threadIdx.x == 0)
        psum[blockIdx.x] = red[0] + red[1] + red[2] + red[3];
}

// K3c: reduce partial sums -> ginv[0] = 1/sum
__global__ __launch_bounds__(1024) void k_rsum(const float* __restrict__ psum, int n,
                                               float* __restrict__ ginv) {
    float lsum = 0.0f;
    for (int i = threadIdx.x; i < n; i += 1024) lsum += psum[i];
    __shared__ float red[16];
    float wsm = wred_sum(lsum);
    if ((threadIdx.x & 63) == 0) red[threadIdx.x >> 6] = wsm;
    __syncthreads();
    if (threadIdx.x == 0) {
        float s = 0.0f;
        for (int i = 0; i < 16; i++) s += red[i];
        ginv[0] = 1.0f / s;
    }
}

// K4: out[src_j] += (p_j * inv) * Wh[dst_j]   (one wave per edge, lane = feature)
__global__ __launch_bounds__(256) void k_scatter(const int* __restrict__ src,
                                                 const int* __restrict__ dst,
                                                 const float* __restrict__ Wh,
                                                 const float* __restrict__ p,
                                                 const float* __restrict__ ginv,
                                                 float* __restrict__ out) {
    int j = blockIdx.x * 4 + (threadIdx.x >> 6);
    int f = threadIdx.x & 63;
    if (j >= N_EDGES) return;
    float att = p[j] * ginv[0];
    int sj = src[j], dj = dst[j];
    atomicAdd(&out[sj * OUT_F + f], att * Wh[dj * OUT_F + f]);
}

__global__ void k_zero(float* __restrict__ out, int n) {
    for (int i = blockIdx.x * blockDim.x + threadIdx.x; i < n; i += gridDim.x * blockDim.x)
        out[i] = 0.0f;
}

__global__ void k_elu(float* __restrict__ out, int n) {
    for (int i = blockIdx.x * blockDim.x + threadIdx.x; i < n; i += gridDim.x * blockDim.x) {
        float v = out[i];
        out[i] = v > 0.0f ? v : expm1f(v);
    }
}

extern "C" void kernel_launch(void* const* d_in, const int* in_sizes, int n_in,
                              void* d_out, int out_size, void* d_ws, size_t ws_size,
                              hipStream_t stream) {
    const float* x  = (const float*)d_in[0];
    const int*   ei = (const int*)d_in[1];
    const float* W  = (const float*)d_in[2];
    const float* a  = (const float*)d_in[3];
    float* out = (float*)d_out;

    const int* src = ei;            // edge_index[0]
    const int* dst = ei + N_EDGES;  // edge_index[1]

    float* ws   = (float*)d_ws;
    float* Wh   = ws;                        // 3,200,000
    float* sv   = Wh + (size_t)N_NODES * OUT_F;
    float* tv   = sv + N_NODES;
    float* e    = tv + N_NODES;              // 800,000
    float* pmax = e + N_EDGES;               // <=1024
    float* psum = pmax + 1024;
    float* gmax = psum + 1024;
    float* ginv = gmax + 1;

    const int NB2 = (N_EDGES + 1023) / 1024;  // 782

    k_zero<<<2048, 256, 0, stream>>>(out, N_NODES * OUT_F);
    k_wh<<<(N_NODES + 3) / 4, 256, 0, stream>>>(x, W, a, Wh, sv, tv);
    k_edge<<<NB2, 256, 0, stream>>>(src, dst, sv, tv, e, pmax);
    k_rmax<<<1, 1024, 0, stream>>>(pmax, NB2, gmax);
    k_exp<<<NB2, 256, 0, stream>>>(e, gmax, psum);
    k_rsum<<<1, 1024, 0, stream>>>(psum, NB2, ginv);
    k_scatter<<<(N_EDGES + 3) / 4, 256, 0, stream>>>(src, dst, Wh, e, ginv, out);
    k_elu<<<2048, 256, 0, stream>>>(out, N_NODES * OUT_F);
}